// Round 1
// baseline (99.576 us; speedup 1.0000x reference)
//
#include <hip/hip_runtime.h>

// SpatialLocalSum: out[b,hw,s] = log( sum_c exp(x[b,hw,c]-mx) * acc[hw,c,s] ) + mx - log(sum_c acc[hw,c,s])
// B=128, HW=1024, C=64, S=64. One block per hw position, 256 threads (4 waves).

typedef __attribute__((ext_vector_type(8))) short s8v;   // 8 bf16 (A/B fragment)
typedef __attribute__((ext_vector_type(4))) float f4v;   // 4 fp32 (C/D fragment)

__device__ __forceinline__ unsigned short f2bf(float f) {
    unsigned int u = __float_as_uint(f);
    u += 0x7FFFu + ((u >> 16) & 1u);   // round-to-nearest-even
    return (unsigned short)(u >> 16);
}

__global__ __launch_bounds__(256) void sls_kernel(
    const float* __restrict__ x,     // [128,1024,64]
    const float* __restrict__ acc,   // [1024,64,64]  (c,s) per hw
    float* __restrict__ out)         // [128,1024,64]
{
    const int hw   = blockIdx.x;     // 0..1023
    const int t    = threadIdx.x;    // 0..255
    const int lane = t & 63;
    const int wave = t >> 6;

    __shared__ s8v   e_sw[1024];       // 16 KB: e (bf16), pre-swizzled in A-frag order
    __shared__ float psum[16][68];     // padded partial column sums
    __shared__ float mx_s[128];
    __shared__ float lsum_s[64];

    // ---------------- global loads (issue everything early) ----------------
    // acc tile, coalesced: thread t covers s0=(t&15)*4 (fixed), c = t/16 + 16*it
    const float4* accv = (const float4*)(acc + (size_t)hw * 4096);
    float4 pa0 = accv[t];
    float4 pa1 = accv[t + 256];
    float4 pa2 = accv[t + 512];
    float4 pa3 = accv[t + 768];

    // x row: thread pair (b = t/2), half = t&1 covers 32 channels
    const int b    = t >> 1;
    const int half = t & 1;
    const float4* xrow = (const float4*)(x + ((size_t)b * 1024 + hw) * 64 + half * 32);
    float4 xv[8];
    #pragma unroll
    for (int j = 0; j < 8; ++j) xv[j] = xrow[j];

    // B fragments straight from global (acc tile is L1/L2-warm from the loads above)
    const int ni   = wave;        // 4 waves cover s in 16-wide tiles
    const int quad = lane >> 4;
    const int nn   = lane & 15;
    float bf_f[2][8];
    #pragma unroll
    for (int ks = 0; ks < 2; ++ks)
        #pragma unroll
        for (int j = 0; j < 8; ++j) {
            int c = ks * 32 + quad * 8 + j;
            bf_f[ks][j] = acc[(size_t)hw * 4096 + c * 64 + ni * 16 + nn];
        }

    // ---------------- phase X: mx, e = exp(x - mx), bf16, A-swizzled store ----------------
    float m = fmaxf(fmaxf(xv[0].x, xv[0].y), fmaxf(xv[0].z, xv[0].w));
    #pragma unroll
    for (int j = 1; j < 8; ++j)
        m = fmaxf(m, fmaxf(fmaxf(xv[j].x, xv[j].y), fmaxf(xv[j].z, xv[j].w)));
    m = fmaxf(m, __shfl_xor(m, 1));        // combine the two halves of the row
    if (half == 0) mx_s[b] = m;

    #pragma unroll
    for (int q = 0; q < 4; ++q) {          // 8 channels per group: c = half*32 + q*8 + j
        float4 u0 = xv[2 * q], u1 = xv[2 * q + 1];
        s8v pk;
        pk[0] = (short)f2bf(__expf(u0.x - m));
        pk[1] = (short)f2bf(__expf(u0.y - m));
        pk[2] = (short)f2bf(__expf(u0.z - m));
        pk[3] = (short)f2bf(__expf(u0.w - m));
        pk[4] = (short)f2bf(__expf(u1.x - m));
        pk[5] = (short)f2bf(__expf(u1.y - m));
        pk[6] = (short)f2bf(__expf(u1.z - m));
        pk[7] = (short)f2bf(__expf(u1.w - m));
        // A-frag order: entry (mi*2+ks)*64 + quad*16 + mrow, elems j=0..7
        e_sw[((b >> 4) * 2 + half) * 64 + q * 16 + (b & 15)] = pk;
    }

    // ---------------- phase P: fp32 partial column sums ----------------
    float4 p;
    p.x = (pa0.x + pa1.x) + (pa2.x + pa3.x);
    p.y = (pa0.y + pa1.y) + (pa2.y + pa3.y);
    p.z = (pa0.z + pa1.z) + (pa2.z + pa3.z);
    p.w = (pa0.w + pa1.w) + (pa2.w + pa3.w);
    *((float4*)&psum[t >> 4][(t & 15) * 4]) = p;

    __syncthreads();

    if (t < 64) {
        float ssum = 0.f;
        #pragma unroll
        for (int r = 0; r < 16; ++r) ssum += psum[r][t];
        lsum_s[t] = __logf(ssum);
    }
    __syncthreads();

    // ---------------- MFMA: per wave, s-tile ni, loop over 8 b-tiles ----------------
    s8v bfrag0, bfrag1;
    #pragma unroll
    for (int j = 0; j < 8; ++j) bfrag0[j] = (short)f2bf(bf_f[0][j]);
    #pragma unroll
    for (int j = 0; j < 8; ++j) bfrag1[j] = (short)f2bf(bf_f[1][j]);

    const float lsum_n = lsum_s[ni * 16 + nn];
    float* outp = out + (size_t)hw * 64 + ni * 16 + nn;

    #pragma unroll
    for (int mi = 0; mi < 8; ++mi) {
        s8v a0 = e_sw[(mi * 2 + 0) * 64 + lane];
        s8v a1 = e_sw[(mi * 2 + 1) * 64 + lane];
        f4v d = {0.f, 0.f, 0.f, 0.f};
        d = __builtin_amdgcn_mfma_f32_16x16x32_bf16(a0, bfrag0, d, 0, 0, 0);
        d = __builtin_amdgcn_mfma_f32_16x16x32_bf16(a1, bfrag1, d, 0, 0, 0);
        #pragma unroll
        for (int r = 0; r < 4; ++r) {
            int b_row = mi * 16 + quad * 4 + r;            // C/D: row=(lane>>4)*4+reg, col=lane&15
            float val = __logf(d[r]) + mx_s[b_row] - lsum_n;
            outp[(size_t)b_row * 65536] = val;             // b_row*1024*64
        }
    }
}

extern "C" void kernel_launch(void* const* d_in, const int* in_sizes, int n_in,
                              void* d_out, int out_size, void* d_ws, size_t ws_size,
                              hipStream_t stream) {
    const float* x   = (const float*)d_in[0];
    const float* acc = (const float*)d_in[1];
    float* out = (float*)d_out;
    (void)in_sizes; (void)n_in; (void)d_ws; (void)ws_size; (void)out_size;
    sls_kernel<<<dim3(1024), dim3(256), 0, stream>>>(x, acc, out);
}

// Round 2
// 96.532 us; speedup vs baseline: 1.0315x; 1.0315x over previous
//
#include <hip/hip_runtime.h>

// SpatialLocalSum: out[b,hw,s] = log( sum_c exp(x[b,hw,c]-mx) * acc[hw,c,s] ) + mx - log(sum_c acc[hw,c,s])
// B=128, HW=1024, C=64, S=64. One block per hw, 256 threads (4 waves), single barrier.

typedef __attribute__((ext_vector_type(8))) short s8v;   // 8 bf16 (A/B fragment)
typedef __attribute__((ext_vector_type(4))) float f4v;   // 4 fp32 (C/D fragment)

__device__ __forceinline__ unsigned short f2bf(float f) {
    unsigned int u = __float_as_uint(f);
    u += 0x7FFFu + ((u >> 16) & 1u);   // round-to-nearest-even
    return (unsigned short)(u >> 16);
}

__global__ __launch_bounds__(256) void sls_kernel(
    const float* __restrict__ x,     // [128,1024,64]
    const float* __restrict__ acc,   // [1024,64,64]  (c,s) per hw
    float* __restrict__ out)         // [128,1024,64]
{
    const int hw   = blockIdx.x;     // 0..1023
    const int t    = threadIdx.x;    // 0..255
    const int lane = t & 63;
    const int quad = lane >> 4;
    const int nn   = lane & 15;
    const int wave = t >> 6;

    // LDS: e (bf16) row-major, row stride 72 elems (144B = 9*16: b128-aligned,
    // 2-way-conflict-free frag reads). 18 KB + 0.5 KB.
    __shared__ unsigned short e_lds[128 * 72];
    __shared__ float mx_s[128];

    // ---------------- issue all global loads up front ----------------
    // x: thread covers rows r0+16*it, 4 consecutive cols. Per wave instr:
    // 4 rows x 256B contiguous (16 lines, vs 64 in the previous version).
    const int r0 = t >> 4;           // 0..15
    const int c0 = (t & 15) * 4;     // 0..60
    const float* xbase = x + (size_t)hw * 64 + c0;
    float4 xv[8];
    #pragma unroll
    for (int it = 0; it < 8; ++it)
        xv[it] = *(const float4*)(xbase + (size_t)(r0 + 16 * it) * 65536);

    // acc: read ONCE, directly in B-fragment order. B[k][n]: n=lane&15, k=quad*8+j (+32*ks).
    const int ni = wave;             // s-tile per wave
    const float* accb = acc + (size_t)hw * 4096 + ni * 16 + nn;
    float bv[2][8];
    #pragma unroll
    for (int ks = 0; ks < 2; ++ks)
        #pragma unroll
        for (int j = 0; j < 8; ++j)
            bv[ks][j] = accb[(ks * 32 + quad * 8 + j) * 64];

    // ---------------- x: row max, exp, bf16, LDS ----------------
    #pragma unroll
    for (int it = 0; it < 8; ++it) {
        float4 v = xv[it];
        float m = fmaxf(fmaxf(v.x, v.y), fmaxf(v.z, v.w));
        m = fmaxf(m, __shfl_xor(m, 1));
        m = fmaxf(m, __shfl_xor(m, 2));
        m = fmaxf(m, __shfl_xor(m, 4));
        m = fmaxf(m, __shfl_xor(m, 8));      // row max across the 16 lanes of this row
        const int row = r0 + 16 * it;
        if (nn == 0) mx_s[row] = m;
        ushort4 pk;
        pk.x = f2bf(__expf(v.x - m));
        pk.y = f2bf(__expf(v.y - m));
        pk.z = f2bf(__expf(v.z - m));
        pk.w = f2bf(__expf(v.w - m));
        *(ushort4*)&e_lds[row * 72 + c0] = pk;   // 8B write, 8B-aligned
    }

    // ---------------- column sums in-register (no LDS, no extra barrier) ----------------
    float csum = 0.f;
    #pragma unroll
    for (int ks = 0; ks < 2; ++ks)
        #pragma unroll
        for (int j = 0; j < 8; ++j) csum += bv[ks][j];
    csum += __shfl_xor(csum, 16);    // combine quads: each lane ends with full sum_c acc[c,s]
    csum += __shfl_xor(csum, 32);
    const float lsum_n = __logf(csum);

    s8v bf0, bf1;
    #pragma unroll
    for (int j = 0; j < 8; ++j) {
        bf0[j] = (short)f2bf(bv[0][j]);
        bf1[j] = (short)f2bf(bv[1][j]);
    }

    __syncthreads();   // the ONLY barrier

    // ---------------- MFMA + epilogue ----------------
    float* outp = out + (size_t)hw * 64 + ni * 16 + nn;
    #pragma unroll
    for (int mi = 0; mi < 8; ++mi) {
        const unsigned short* rowp = &e_lds[(mi * 16 + nn) * 72];
        s8v a0 = *(const s8v*)(rowp + quad * 8);        // k = quad*8+j, cols 0..31
        s8v a1 = *(const s8v*)(rowp + 32 + quad * 8);   // cols 32..63
        f4v d = {0.f, 0.f, 0.f, 0.f};
        d = __builtin_amdgcn_mfma_f32_16x16x32_bf16(a0, bf0, d, 0, 0, 0);
        d = __builtin_amdgcn_mfma_f32_16x16x32_bf16(a1, bf1, d, 0, 0, 0);
        #pragma unroll
        for (int r = 0; r < 4; ++r) {
            const int b_row = mi * 16 + quad * 4 + r;   // C/D: row=(lane>>4)*4+r, col=lane&15
            outp[(size_t)b_row * 65536] = __logf(d[r]) + mx_s[b_row] - lsum_n;
        }
    }
}

extern "C" void kernel_launch(void* const* d_in, const int* in_sizes, int n_in,
                              void* d_out, int out_size, void* d_ws, size_t ws_size,
                              hipStream_t stream) {
    const float* x   = (const float*)d_in[0];
    const float* acc = (const float*)d_in[1];
    float* out = (float*)d_out;
    (void)in_sizes; (void)n_in; (void)d_ws; (void)ws_size; (void)out_size;
    sls_kernel<<<dim3(1024), dim3(256), 0, stream>>>(x, acc, out);
}